// Round 1
// baseline (535.628 us; speedup 1.0000x reference)
//
#include <hip/hip_runtime.h>
#include <cstdint>
#include <cstddef>

#define N_NODES 50000
#define N_EDGES 800000
#define F_IN    128
#define F_HID   256
#define F_OUT   40

// ---------------------------------------------------------------------------
// Pass 1: degree histogram (float atomics into zeroed buffers)
// ---------------------------------------------------------------------------
__global__ __launch_bounds__(256) void degree_kernel(
    const int* __restrict__ src, const int* __restrict__ dst,
    float* __restrict__ deg_out, float* __restrict__ deg_in) {
  int i = blockIdx.x * 256 + threadIdx.x;
  if (i < N_EDGES) {
    atomicAdd(&deg_out[src[i]], 1.0f);
    atomicAdd(&deg_in[dst[i]], 1.0f);
  }
}

// ---------------------------------------------------------------------------
// Pass 2: single-block exclusive scan of in-degrees -> row_ptr (CSR by dst)
// ---------------------------------------------------------------------------
__global__ __launch_bounds__(1024) void scan_kernel(
    const float* __restrict__ deg_in, int* __restrict__ row_ptr) {
  __shared__ int part[1024];
  const int n = N_NODES;
  int tid = threadIdx.x;
  int chunk = (n + 1023) / 1024;
  int b = tid * chunk;
  int e = min(b + chunk, n);
  int s = 0;
  for (int i = b; i < e; ++i) s += (int)deg_in[i];
  part[tid] = s;
  __syncthreads();
  // Hillis-Steele inclusive scan over 1024 partials
  for (int off = 1; off < 1024; off <<= 1) {
    int v = (tid >= off) ? part[tid - off] : 0;
    __syncthreads();
    part[tid] += v;
    __syncthreads();
  }
  int excl = (tid > 0) ? part[tid - 1] : 0;
  for (int i = b; i < e; ++i) {
    row_ptr[i] = excl;
    excl += (int)deg_in[i];
  }
  if (tid == 1023) row_ptr[n] = part[1023];
}

// ---------------------------------------------------------------------------
// Pass 3: degree -> norm (in place), cursor = row_ptr copy
// ---------------------------------------------------------------------------
__global__ __launch_bounds__(256) void norm_cursor_kernel(
    float* __restrict__ deg_out, float* __restrict__ deg_in,
    const int* __restrict__ row_ptr, int* __restrict__ cursor) {
  int i = blockIdx.x * 256 + threadIdx.x;
  if (i < N_NODES) {
    cursor[i] = row_ptr[i];
    deg_out[i] = 1.0f / sqrtf(fmaxf(deg_out[i], 1.0f));
    deg_in[i]  = 1.0f / sqrtf(fmaxf(deg_in[i], 1.0f));
  }
}

// ---------------------------------------------------------------------------
// Pass 4: scatter edges into CSR buckets
// ---------------------------------------------------------------------------
__global__ __launch_bounds__(256) void scatter_kernel(
    const int* __restrict__ src, const int* __restrict__ dst,
    int* __restrict__ cursor, int* __restrict__ csr_src) {
  int i = blockIdx.x * 256 + threadIdx.x;
  if (i < N_EDGES) {
    int d = dst[i];
    int p = atomicAdd(&cursor[d], 1);
    csr_src[p] = src[i];
  }
}

// ---------------------------------------------------------------------------
// Pass 5: layer-1 aggregation at dim 128. One wave per dst node.
// agg1[v] = norm_dst[v] * sum_{s in N(v)} norm_src[s] * feat[s]
// ---------------------------------------------------------------------------
__global__ __launch_bounds__(256) void agg1_kernel(
    const float* __restrict__ feat, const int* __restrict__ row_ptr,
    const int* __restrict__ csr_src, const float* __restrict__ norm_src,
    const float* __restrict__ norm_dst, float* __restrict__ out) {
  int wid = (blockIdx.x * 256 + threadIdx.x) >> 6;  // node id
  int lane = threadIdx.x & 63;
  if (wid >= N_NODES) return;
  int beg = row_ptr[wid], end = row_ptr[wid + 1];
  float ax = 0.f, ay = 0.f;
  for (int e = beg; e < end; ++e) {
    int s = csr_src[e];
    float ns = norm_src[s];
    float2 f = *(const float2*)(feat + (size_t)s * F_IN + lane * 2);
    ax += f.x * ns;
    ay += f.y * ns;
  }
  float nd = norm_dst[wid];
  float2 r;
  r.x = ax * nd;
  r.y = ay * nd;
  *(float2*)(out + (size_t)wid * F_IN + lane * 2) = r;
}

// ---------------------------------------------------------------------------
// fp32 tiled GEMM. EPI 0: C = relu(acc + bias[col])   (layer 1)
//                  EPI 1: C = acc * rowscale[row]     (layer 2 pre-agg)
// ---------------------------------------------------------------------------
template <int BM, int BN, int BK, int TM, int TN, int EPI>
__global__ __launch_bounds__(256) void gemm_kernel(
    const float* __restrict__ A, const float* __restrict__ B,
    const float* __restrict__ bias, const float* __restrict__ rowscale,
    float* __restrict__ C, int M, int N, int K) {
  constexpr int TX = BN / TN;
  constexpr int TY = BM / TM;
  static_assert(TX * TY == 256, "bad thread tiling");
  __shared__ float As[BK][BM + 1];
  __shared__ float Bs[BK][BN];
  int tid = threadIdx.x;
  int tx = tid % TX, ty = tid / TX;
  int row0 = blockIdx.x * BM;
  int col0 = blockIdx.y * BN;
  float acc[TM][TN];
#pragma unroll
  for (int i = 0; i < TM; ++i)
#pragma unroll
    for (int j = 0; j < TN; ++j) acc[i][j] = 0.f;

  for (int k0 = 0; k0 < K; k0 += BK) {
    // A tile (BM x BK) -> As transposed
    constexpr int A4 = BM * BK / 4;
    for (int idx = tid; idx < A4; idx += 256) {
      int r = idx / (BK / 4);
      int c4 = idx % (BK / 4);
      int row = row0 + r;
      float4 v = (row < M) ? *(const float4*)(A + (size_t)row * K + k0 + c4 * 4)
                           : make_float4(0.f, 0.f, 0.f, 0.f);
      As[c4 * 4 + 0][r] = v.x;
      As[c4 * 4 + 1][r] = v.y;
      As[c4 * 4 + 2][r] = v.z;
      As[c4 * 4 + 3][r] = v.w;
    }
    // B tile (BK x BN)
    constexpr int B4 = BK * BN / 4;
    for (int idx = tid; idx < B4; idx += 256) {
      int r = idx / (BN / 4);
      int c4 = idx % (BN / 4);
      float4 v = *(const float4*)(B + (size_t)(k0 + r) * N + col0 + c4 * 4);
      *(float4*)(&Bs[r][c4 * 4]) = v;
    }
    __syncthreads();
#pragma unroll
    for (int k = 0; k < BK; ++k) {
      float a[TM], b[TN];
#pragma unroll
      for (int i = 0; i < TM; ++i) a[i] = As[k][ty * TM + i];
#pragma unroll
      for (int j = 0; j < TN; ++j) b[j] = Bs[k][tx * TN + j];
#pragma unroll
      for (int i = 0; i < TM; ++i)
#pragma unroll
        for (int j = 0; j < TN; ++j) acc[i][j] += a[i] * b[j];
    }
    __syncthreads();
  }

#pragma unroll
  for (int i = 0; i < TM; ++i) {
    int row = row0 + ty * TM + i;
    if (row >= M) continue;
    float rs = (EPI == 1) ? rowscale[row] : 1.0f;
#pragma unroll
    for (int j = 0; j < TN; ++j) {
      int col = col0 + tx * TN + j;
      float v = acc[i][j];
      if (EPI == 0) {
        v += bias[col];
        v = fmaxf(v, 0.f);
      } else {
        v *= rs;
      }
      C[(size_t)row * N + col] = v;
    }
  }
}

// ---------------------------------------------------------------------------
// Pass 8: layer-2 aggregation at dim 40 + bias + log_softmax. Wave per node.
// ---------------------------------------------------------------------------
__global__ __launch_bounds__(256) void agg2_softmax_kernel(
    const float* __restrict__ t, const int* __restrict__ row_ptr,
    const int* __restrict__ csr_src, const float* __restrict__ norm_dst,
    const float* __restrict__ b2, float* __restrict__ out) {
  int wid = (blockIdx.x * 256 + threadIdx.x) >> 6;  // node id
  int lane = threadIdx.x & 63;
  if (wid >= N_NODES) return;
  int beg = row_ptr[wid], end = row_ptr[wid + 1];
  bool active = lane < F_OUT;
  float acc = 0.f;
  for (int e = beg; e < end; ++e) {
    int s = csr_src[e];
    if (active) acc += t[(size_t)s * F_OUT + lane];
  }
  float v = active ? acc * norm_dst[wid] + b2[lane] : -INFINITY;
  // max over lanes 0..39 (inactive contribute -inf)
  float m = v;
#pragma unroll
  for (int off = 32; off > 0; off >>= 1) m = fmaxf(m, __shfl_xor(m, off));
  float ex = active ? expf(v - m) : 0.f;
  float s = ex;
#pragma unroll
  for (int off = 32; off > 0; off >>= 1) s += __shfl_xor(s, off);
  if (active) out[(size_t)wid * F_OUT + lane] = (v - m) - logf(s);
}

// ---------------------------------------------------------------------------
extern "C" void kernel_launch(void* const* d_in, const int* in_sizes, int n_in,
                              void* d_out, int out_size, void* d_ws, size_t ws_size,
                              hipStream_t stream) {
  const float* feat = (const float*)d_in[0];
  const float* W1   = (const float*)d_in[1];
  const float* b1   = (const float*)d_in[2];
  const float* W2   = (const float*)d_in[3];
  const float* b2   = (const float*)d_in[4];
  const int*   src  = (const int*)d_in[5];
  const int*   dst  = (const int*)d_in[6];
  float* out = (float*)d_out;

  char* p = (char*)d_ws;
  auto alloc = [&](size_t bytes) {
    char* r = p;
    p += (bytes + 255) & ~(size_t)255;
    return r;
  };
  float* norm_src = (float*)alloc((size_t)N_NODES * 4);       // deg_out -> norm
  float* norm_dst = (float*)alloc((size_t)N_NODES * 4);       // deg_in  -> norm
  int*   row_ptr  = (int*)alloc((size_t)(N_NODES + 1) * 4);
  int*   cursor   = (int*)alloc((size_t)N_NODES * 4);
  int*   csr_src  = (int*)alloc((size_t)N_EDGES * 4);
  float* agg1     = (float*)alloc((size_t)N_NODES * F_IN * 4);
  float* h        = (float*)alloc((size_t)N_NODES * F_HID * 4);
  float* t        = (float*)alloc((size_t)N_NODES * F_OUT * 4);

  // zero the two degree accumulators (contiguous region)
  size_t zero_bytes = (size_t)((char*)row_ptr - (char*)norm_src);
  hipMemsetAsync(norm_src, 0, zero_bytes, stream);

  degree_kernel<<<(N_EDGES + 255) / 256, 256, 0, stream>>>(src, dst, norm_src, norm_dst);
  scan_kernel<<<1, 1024, 0, stream>>>(norm_dst, row_ptr);
  norm_cursor_kernel<<<(N_NODES + 255) / 256, 256, 0, stream>>>(norm_src, norm_dst, row_ptr, cursor);
  scatter_kernel<<<(N_EDGES + 255) / 256, 256, 0, stream>>>(src, dst, cursor, csr_src);
  agg1_kernel<<<(N_NODES * 64 + 255) / 256, 256, 0, stream>>>(feat, row_ptr, csr_src, norm_src, norm_dst, agg1);
  gemm_kernel<64, 64, 32, 4, 4, 0><<<dim3((N_NODES + 63) / 64, F_HID / 64), 256, 0, stream>>>(
      agg1, W1, b1, nullptr, h, N_NODES, F_HID, F_IN);
  gemm_kernel<64, 40, 32, 2, 5, 1><<<dim3((N_NODES + 63) / 64, 1), 256, 0, stream>>>(
      h, W2, nullptr, norm_src, t, N_NODES, F_OUT, F_HID);
  agg2_softmax_kernel<<<(N_NODES * 64 + 255) / 256, 256, 0, stream>>>(t, row_ptr, csr_src, norm_dst, b2, out);
}

// Round 3
// 381.874 us; speedup vs baseline: 1.4026x; 1.4026x over previous
//
#include <hip/hip_runtime.h>
#include <cstdint>
#include <cstddef>

#define N_NODES 50000
#define N_EDGES 800000
#define F_IN    128
#define F_HID   256
#define F_OUT   40
#define NB      196   // ceil(N_NODES / 256)

// ---------------------------------------------------------------------------
// Pass 1: degree histogram (int atomics into zeroed buffers)
// ---------------------------------------------------------------------------
__global__ __launch_bounds__(256) void degree_kernel(
    const int* __restrict__ src, const int* __restrict__ dst,
    int* __restrict__ deg_out, int* __restrict__ deg_in) {
  int i = blockIdx.x * 256 + threadIdx.x;
  if (i < N_EDGES) {
    atomicAdd(&deg_out[src[i]], 1);
    atomicAdd(&deg_in[dst[i]], 1);
  }
}

// ---------------------------------------------------------------------------
// Pass 2a: per-block (256-node chunk) sums of in-degree
// ---------------------------------------------------------------------------
__global__ __launch_bounds__(256) void block_sum_kernel(
    const int* __restrict__ deg_in, int* __restrict__ bsum) {
  __shared__ int arr[256];
  int node = blockIdx.x * 256 + threadIdx.x;
  arr[threadIdx.x] = (node < N_NODES) ? deg_in[node] : 0;
  __syncthreads();
  for (int off = 128; off > 0; off >>= 1) {
    if (threadIdx.x < off) arr[threadIdx.x] += arr[threadIdx.x + off];
    __syncthreads();
  }
  if (threadIdx.x == 0) bsum[blockIdx.x] = arr[0];
}

// ---------------------------------------------------------------------------
// Pass 2b: exclusive scan of the NB block sums (single small block)
// ---------------------------------------------------------------------------
__global__ __launch_bounds__(256) void scan_bsum_kernel(int* __restrict__ bsum) {
  __shared__ int arr[256];
  int tid = threadIdx.x;
  int v = (tid < NB) ? bsum[tid] : 0;
  arr[tid] = v;
  __syncthreads();
  for (int off = 1; off < 256; off <<= 1) {
    int t = (tid >= off) ? arr[tid - off] : 0;
    __syncthreads();
    arr[tid] += t;
    __syncthreads();
  }
  if (tid < NB) bsum[tid] = arr[tid] - v;  // exclusive
}

// ---------------------------------------------------------------------------
// Pass 2c: finalize — block-local scan -> row_ptr & cursor, plus norms
// ---------------------------------------------------------------------------
__global__ __launch_bounds__(256) void finalize_kernel(
    const int* __restrict__ deg_out, const int* __restrict__ deg_in,
    const int* __restrict__ bsum, int* __restrict__ row_ptr,
    int* __restrict__ cursor, float* __restrict__ norm_src,
    float* __restrict__ norm_dst) {
  __shared__ int arr[256];
  int tid = threadIdx.x;
  int node = blockIdx.x * 256 + tid;
  int di = (node < N_NODES) ? deg_in[node] : 0;
  arr[tid] = di;
  __syncthreads();
  for (int off = 1; off < 256; off <<= 1) {
    int t = (tid >= off) ? arr[tid - off] : 0;
    __syncthreads();
    arr[tid] += t;
    __syncthreads();
  }
  if (node < N_NODES) {
    int rp = bsum[blockIdx.x] + arr[tid] - di;  // exclusive prefix
    row_ptr[node] = rp;
    cursor[node] = rp;
    norm_dst[node] = 1.0f / sqrtf(fmaxf((float)di, 1.0f));
    norm_src[node] = 1.0f / sqrtf(fmaxf((float)deg_out[node], 1.0f));
  }
  if (blockIdx.x == 0 && tid == 0) row_ptr[N_NODES] = N_EDGES;
}

// ---------------------------------------------------------------------------
// Pass 3: scatter edges into CSR buckets (by dst)
// ---------------------------------------------------------------------------
__global__ __launch_bounds__(256) void scatter_kernel(
    const int* __restrict__ src, const int* __restrict__ dst,
    int* __restrict__ cursor, int* __restrict__ csr_src) {
  int i = blockIdx.x * 256 + threadIdx.x;
  if (i < N_EDGES) {
    int d = dst[i];
    int p = atomicAdd(&cursor[d], 1);
    csr_src[p] = src[i];
  }
}

// ---------------------------------------------------------------------------
// Pass 4: xs = feat * norm_src[row]  (removes per-edge 4B random norm loads)
// ---------------------------------------------------------------------------
__global__ __launch_bounds__(256) void prescale_kernel(
    const float* __restrict__ feat, const float* __restrict__ norm_src,
    float* __restrict__ xs) {
  int i = blockIdx.x * 256 + threadIdx.x;  // one float4 per thread, exact grid
  int row = i >> 5;                        // 32 float4 per row
  float4 v = ((const float4*)feat)[i];
  float ns = norm_src[row];
  v.x *= ns; v.y *= ns; v.z *= ns; v.w *= ns;
  ((float4*)xs)[i] = v;
}

// ---------------------------------------------------------------------------
// Pass 5: layer-1 aggregation at dim 128. One wave per dst node.
// Two 32-lane groups each fetch a full 512B row (float4/lane): 2 edges in
// flight; index prefetched one iteration ahead.
// ---------------------------------------------------------------------------
__global__ __launch_bounds__(256) void agg1_kernel(
    const float* __restrict__ xs, const int* __restrict__ row_ptr,
    const int* __restrict__ csr_src, const float* __restrict__ norm_dst,
    float* __restrict__ out) {
  int wid = (blockIdx.x * 256 + threadIdx.x) >> 6;
  if (wid >= N_NODES) return;
  int lane = threadIdx.x & 63;
  int g = lane >> 5;        // group 0/1 -> edges beg+g, beg+g+2, ...
  int l32 = lane & 31;
  int beg = row_ptr[wid], end = row_ptr[wid + 1];
  float4 acc = make_float4(0.f, 0.f, 0.f, 0.f);
  int e = beg + g;
  if (e < end) {
    int s = csr_src[e];
    while (true) {
      int en = e + 2;
      int sn = (en < end) ? csr_src[en] : 0;   // prefetch next index
      float4 f = *(const float4*)(xs + (size_t)s * F_IN + (l32 << 2));
      acc.x += f.x; acc.y += f.y; acc.z += f.z; acc.w += f.w;
      if (en >= end) break;
      e = en; s = sn;
    }
  }
  // combine the two halves
  acc.x += __shfl_xor(acc.x, 32);
  acc.y += __shfl_xor(acc.y, 32);
  acc.z += __shfl_xor(acc.z, 32);
  acc.w += __shfl_xor(acc.w, 32);
  if (g == 0) {
    float nd = norm_dst[wid];
    acc.x *= nd; acc.y *= nd; acc.z *= nd; acc.w *= nd;
    *(float4*)(out + (size_t)wid * F_IN + (l32 << 2)) = acc;
  }
}

// ---------------------------------------------------------------------------
// fp32 GEMM, layer 1: h = relu(agg1 @ W1 + b1). 128x64x32, TM=8 TN=4.
// ---------------------------------------------------------------------------
__global__ __launch_bounds__(256) void gemm1_kernel(
    const float* __restrict__ A, const float* __restrict__ B,
    const float* __restrict__ bias, float* __restrict__ C, int M) {
  constexpr int BM = 128, BN = 64, BK = 32, TM = 8, TN = 4;
  constexpr int N = F_HID, K = F_IN;
  __shared__ float As[BK][BM + 4];
  __shared__ float Bs[BK][BN];
  int tid = threadIdx.x;
  int tx = tid % (BN / TN);  // 0..15
  int ty = tid / (BN / TN);  // 0..15
  int row0 = blockIdx.x * BM;
  int col0 = blockIdx.y * BN;
  float acc[TM][TN];
#pragma unroll
  for (int i = 0; i < TM; ++i)
#pragma unroll
    for (int j = 0; j < TN; ++j) acc[i][j] = 0.f;

  for (int k0 = 0; k0 < K; k0 += BK) {
#pragma unroll
    for (int idx = tid; idx < BM * BK / 4; idx += 256) {
      int r = idx / (BK / 4);
      int c4 = idx % (BK / 4);
      int row = row0 + r;
      float4 v = (row < M) ? *(const float4*)(A + (size_t)row * K + k0 + c4 * 4)
                           : make_float4(0.f, 0.f, 0.f, 0.f);
      As[c4 * 4 + 0][r] = v.x;
      As[c4 * 4 + 1][r] = v.y;
      As[c4 * 4 + 2][r] = v.z;
      As[c4 * 4 + 3][r] = v.w;
    }
#pragma unroll
    for (int idx = tid; idx < BK * BN / 4; idx += 256) {
      int r = idx / (BN / 4);
      int c4 = idx % (BN / 4);
      *(float4*)(&Bs[r][c4 * 4]) =
          *(const float4*)(B + (size_t)(k0 + r) * N + col0 + c4 * 4);
    }
    __syncthreads();
#pragma unroll
    for (int k = 0; k < BK; ++k) {
      float4 a0 = *(const float4*)(&As[k][ty * TM]);
      float4 a1 = *(const float4*)(&As[k][ty * TM + 4]);
      float4 b0 = *(const float4*)(&Bs[k][tx * TN]);
      float a[TM] = {a0.x, a0.y, a0.z, a0.w, a1.x, a1.y, a1.z, a1.w};
      float b[TN] = {b0.x, b0.y, b0.z, b0.w};
#pragma unroll
      for (int i = 0; i < TM; ++i)
#pragma unroll
        for (int j = 0; j < TN; ++j) acc[i][j] += a[i] * b[j];
    }
    __syncthreads();
  }

#pragma unroll
  for (int i = 0; i < TM; ++i) {
    int row = row0 + ty * TM + i;
    if (row >= M) continue;
    float4 bv = *(const float4*)(bias + col0 + tx * TN);
    float4 v = make_float4(fmaxf(acc[i][0] + bv.x, 0.f),
                           fmaxf(acc[i][1] + bv.y, 0.f),
                           fmaxf(acc[i][2] + bv.z, 0.f),
                           fmaxf(acc[i][3] + bv.w, 0.f));
    *(float4*)(C + (size_t)row * N + col0 + tx * TN) = v;
  }
}

// ---------------------------------------------------------------------------
// fp32 GEMM, layer 2: t = (h @ W2) * norm_src[row]. 128x40x32, 320 threads.
// ---------------------------------------------------------------------------
__global__ __launch_bounds__(320) void gemm2_kernel(
    const float* __restrict__ A, const float* __restrict__ B,
    const float* __restrict__ rowscale, float* __restrict__ C, int M) {
  constexpr int BM = 128, BN = 40, BK = 32, TM = 4, TN = 4;
  constexpr int N = F_OUT, K = F_HID;
  __shared__ float As[BK][BM + 4];
  __shared__ float Bs[BK][BN];
  int tid = threadIdx.x;
  int tx = tid % (BN / TN);  // 0..9
  int ty = tid / (BN / TN);  // 0..31
  int row0 = blockIdx.x * BM;
  float acc[TM][TN];
#pragma unroll
  for (int i = 0; i < TM; ++i)
#pragma unroll
    for (int j = 0; j < TN; ++j) acc[i][j] = 0.f;

  for (int k0 = 0; k0 < K; k0 += BK) {
    for (int idx = tid; idx < BM * BK / 4; idx += 320) {
      int r = idx / (BK / 4);
      int c4 = idx % (BK / 4);
      int row = row0 + r;
      float4 v = (row < M) ? *(const float4*)(A + (size_t)row * K + k0 + c4 * 4)
                           : make_float4(0.f, 0.f, 0.f, 0.f);
      As[c4 * 4 + 0][r] = v.x;
      As[c4 * 4 + 1][r] = v.y;
      As[c4 * 4 + 2][r] = v.z;
      As[c4 * 4 + 3][r] = v.w;
    }
    {  // B tile: 32x40 floats = 320 float4, one per thread
      int r = tid / 10;
      int c4 = tid % 10;
      *(float4*)(&Bs[r][c4 * 4]) =
          *(const float4*)(B + (size_t)(k0 + r) * N + c4 * 4);
    }
    __syncthreads();
#pragma unroll
    for (int k = 0; k < BK; ++k) {
      float4 a0 = *(const float4*)(&As[k][ty * TM]);
      float4 b0 = *(const float4*)(&Bs[k][tx * TN]);
      float a[TM] = {a0.x, a0.y, a0.z, a0.w};
      float b[TN] = {b0.x, b0.y, b0.z, b0.w};
#pragma unroll
      for (int i = 0; i < TM; ++i)
#pragma unroll
        for (int j = 0; j < TN; ++j) acc[i][j] += a[i] * b[j];
    }
    __syncthreads();
  }

#pragma unroll
  for (int i = 0; i < TM; ++i) {
    int row = row0 + ty * TM + i;
    if (row >= M) continue;
    float rs = rowscale[row];
    float4 v = make_float4(acc[i][0] * rs, acc[i][1] * rs,
                           acc[i][2] * rs, acc[i][3] * rs);
    *(float4*)(C + (size_t)row * N + tx * TN) = v;
  }
}

// ---------------------------------------------------------------------------
// Pass 8: layer-2 aggregation at dim 40 + bias + log_softmax.
// Four 16-lane groups, each fetching a 160B row (float4/lane, 10 active):
// 4 edges in flight per wave.
// ---------------------------------------------------------------------------
__global__ __launch_bounds__(256) void agg2_softmax_kernel(
    const float* __restrict__ t, const int* __restrict__ row_ptr,
    const int* __restrict__ csr_src, const float* __restrict__ norm_dst,
    const float* __restrict__ b2, float* __restrict__ out) {
  int wid = (blockIdx.x * 256 + threadIdx.x) >> 6;
  if (wid >= N_NODES) return;
  int lane = threadIdx.x & 63;
  int g = lane >> 4;        // group 0..3 -> edges beg+g, beg+g+4, ...
  int l16 = lane & 15;
  bool act = l16 < 10;      // 10 float4 = 40 floats
  int beg = row_ptr[wid], end = row_ptr[wid + 1];
  float4 acc = make_float4(0.f, 0.f, 0.f, 0.f);
  for (int e = beg + g; e < end; e += 4) {
    int s = csr_src[e];
    if (act) {
      float4 f = *(const float4*)(t + (size_t)s * F_OUT + (l16 << 2));
      acc.x += f.x; acc.y += f.y; acc.z += f.z; acc.w += f.w;
    }
  }
  // combine 4 groups (xor 16, 32) — every group ends with the full sum
#pragma unroll
  for (int off = 16; off <= 32; off <<= 1) {
    acc.x += __shfl_xor(acc.x, off);
    acc.y += __shfl_xor(acc.y, off);
    acc.z += __shfl_xor(acc.z, off);
    acc.w += __shfl_xor(acc.w, off);
  }
  float nd = norm_dst[wid];
  float4 v;
  if (act) {
    float4 bv = *(const float4*)(b2 + (l16 << 2));
    v = make_float4(acc.x * nd + bv.x, acc.y * nd + bv.y,
                    acc.z * nd + bv.z, acc.w * nd + bv.w);
  } else {
    v = make_float4(-INFINITY, -INFINITY, -INFINITY, -INFINITY);
  }
  // max over the 40 values (within each 16-lane group)
  float m = fmaxf(fmaxf(v.x, v.y), fmaxf(v.z, v.w));
#pragma unroll
  for (int off = 1; off <= 8; off <<= 1) m = fmaxf(m, __shfl_xor(m, off));
  float ex = act ? (expf(v.x - m) + expf(v.y - m) + expf(v.z - m) + expf(v.w - m)) : 0.f;
#pragma unroll
  for (int off = 1; off <= 8; off <<= 1) ex += __shfl_xor(ex, off);
  float ls = logf(ex);
  if (g == 0 && act) {
    float4 r = make_float4(v.x - m - ls, v.y - m - ls, v.z - m - ls, v.w - m - ls);
    *(float4*)(out + (size_t)wid * F_OUT + (l16 << 2)) = r;
  }
}

// ---------------------------------------------------------------------------
extern "C" void kernel_launch(void* const* d_in, const int* in_sizes, int n_in,
                              void* d_out, int out_size, void* d_ws, size_t ws_size,
                              hipStream_t stream) {
  const float* feat = (const float*)d_in[0];
  const float* W1   = (const float*)d_in[1];
  const float* b1   = (const float*)d_in[2];
  const float* W2   = (const float*)d_in[3];
  const float* b2   = (const float*)d_in[4];
  const int*   src  = (const int*)d_in[5];
  const int*   dst  = (const int*)d_in[6];
  float* out = (float*)d_out;

  char* p = (char*)d_ws;
  auto alloc = [&](size_t bytes) {
    char* r = p;
    p += (bytes + 255) & ~(size_t)255;
    return r;
  };
  int*   deg_out  = (int*)alloc((size_t)N_NODES * 4);
  int*   deg_in   = (int*)alloc((size_t)N_NODES * 4);
  int*   bsum     = (int*)alloc((size_t)NB * 4);
  int*   row_ptr  = (int*)alloc((size_t)(N_NODES + 1) * 4);
  int*   cursor   = (int*)alloc((size_t)N_NODES * 4);
  int*   csr_src  = (int*)alloc((size_t)N_EDGES * 4);
  float* norm_src = (float*)alloc((size_t)N_NODES * 4);
  float* norm_dst = (float*)alloc((size_t)N_NODES * 4);
  float* t        = (float*)alloc((size_t)N_NODES * F_OUT * 4);
  // h overlays xs (xs dead before gemm1 writes h); agg1 stays separate.
  float* xs       = (float*)alloc((size_t)N_NODES * F_HID * 4);  // 51.2MB; xs uses first half
  float* h        = xs;                                          // full 256-wide
  float* agg1     = (float*)alloc((size_t)N_NODES * F_IN * 4);

  // zero BOTH degree accumulators — span computed from actual pointers so the
  // 256B alloc padding is covered (previous version missed the last 192B of
  // deg_in -> poisoned degrees -> OOB scatter).
  size_t zero_bytes = (size_t)((char*)bsum - (char*)deg_out);
  hipMemsetAsync(deg_out, 0, zero_bytes, stream);

  degree_kernel<<<(N_EDGES + 255) / 256, 256, 0, stream>>>(src, dst, deg_out, deg_in);
  block_sum_kernel<<<NB, 256, 0, stream>>>(deg_in, bsum);
  scan_bsum_kernel<<<1, 256, 0, stream>>>(bsum);
  finalize_kernel<<<NB, 256, 0, stream>>>(deg_out, deg_in, bsum, row_ptr, cursor,
                                          norm_src, norm_dst);
  scatter_kernel<<<(N_EDGES + 255) / 256, 256, 0, stream>>>(src, dst, cursor, csr_src);
  prescale_kernel<<<N_NODES * (F_IN / 4) / 256, 256, 0, stream>>>(feat, norm_src, xs);
  agg1_kernel<<<(N_NODES * 64) / 256 + 1, 256, 0, stream>>>(xs, row_ptr, csr_src,
                                                            norm_dst, agg1);
  // gemm1 reads agg1, writes h (overlays xs — xs is dead now)
  gemm1_kernel<<<dim3((N_NODES + 127) / 128, F_HID / 64), 256, 0, stream>>>(
      agg1, W1, b1, h, N_NODES);
  gemm2_kernel<<<(N_NODES + 127) / 128, 320, 0, stream>>>(h, W2, norm_src, t, N_NODES);
  agg2_softmax_kernel<<<(N_NODES * 64) / 256 + 1, 256, 0, stream>>>(
      t, row_ptr, csr_src, norm_dst, b2, out);
}